// Round 11
// baseline (285.473 us; speedup 1.0000x reference)
//
#include <hip/hip_runtime.h>

// ---------------------------------------------------------------------------
// CNN + FC + 2x GraphSAGE, collapsed to scalar fields (GNN part is linear).
// fc2 + both SAGE layers folded into 86 coefficients (k_scan).
// k_mlp: 4 threads/row (conv branch q each), register x-loads, feat exchange
// via padded LDS, coef tail reduced with __shfl_xor(4). LDS 13.5KB +
// __launch_bounds__(256,6) -> >=6 blocks/CU (24 waves) for load-latency hiding.
// Aggregation via per-call CSR + register gather; adj read directly per lane
// (no shfl dependency chain), 16 independent loads in flight per chunk.
// ---------------------------------------------------------------------------

#define WFEAT 1266   // weights: conv 480 | bias 20 | f1w 660 (stride 33) | f1b 20 | coef 86
#define LDS_TOT 3378 // + 64 x 33 feat

__global__ void k_count(const int* __restrict__ dst, int E, int* __restrict__ cnt) {
  int e = blockIdx.x * blockDim.x + threadIdx.x;
  if (e < E) atomicAdd(&cnt[dst[e]], 1);
}

// single block: weight folding (threads 0..20) + exclusive scan of cnt
__global__ __launch_bounds__(1024) void k_scan(
    const int* __restrict__ cnt, int N,
    int* __restrict__ row_ptr, int* __restrict__ cursor,
    const float* __restrict__ f2w, const float* __restrict__ f2b,
    const float* __restrict__ g1_wl, const float* __restrict__ g1_bl,
    const float* __restrict__ g1_wr, const float* __restrict__ g2_wl,
    const float* __restrict__ g2_wr, float* __restrict__ coef) {
  int t = threadIdx.x;

  if (t < 21) {
    float a[5], r1[5], c[5], r2[5];
#pragma unroll
    for (int k = 0; k < 5; ++k) { a[k] = 0.f; r1[k] = 0.f; c[k] = 0.f; r2[k] = 0.f; }
#pragma unroll
    for (int j = 0; j < 20; ++j) {
      float wl2 = g2_wl[j], wr2 = g2_wr[j];
#pragma unroll
      for (int k = 0; k < 5; ++k) {
        float wl1 = g1_wl[j * 5 + k], wr1 = g1_wr[j * 5 + k];
        a[k]  = fmaf(wl2, wl1, a[k]);
        r1[k] = fmaf(wr2, wl1, r1[k]);
        c[k]  = fmaf(wl2, wr1, c[k]);
        r2[k] = fmaf(wr2, wr1, r2[k]);
      }
    }
    if (t < 20) {
      float A = 0.f, R1 = 0.f, C = 0.f, R2 = 0.f;
#pragma unroll
      for (int k = 0; k < 5; ++k) {
        float w = f2w[k * 20 + t];
        A  = fmaf(a[k],  w, A);
        R1 = fmaf(r1[k], w, R1);
        C  = fmaf(c[k],  w, C);
        R2 = fmaf(r2[k], w, R2);
      }
      coef[t] = A; coef[20 + t] = R1; coef[40 + t] = C; coef[60 + t] = R2;
    } else {
      float ca = 0.f, cr1 = 0.f, cc = 0.f, cr2 = 0.f;
#pragma unroll
      for (int k = 0; k < 5; ++k) {
        float b = f2b[k];
        ca = fmaf(a[k], b, ca);  cr1 = fmaf(r1[k], b, cr1);
        cc = fmaf(c[k], b, cc);  cr2 = fmaf(r2[k], b, cr2);
      }
      coef[80] = ca; coef[81] = cr1; coef[82] = cc; coef[83] = cr2;
      float kb1 = 0.f, kb2 = 0.f;
#pragma unroll
      for (int j = 0; j < 20; ++j) {
        kb1 = fmaf(g2_wl[j], g1_bl[j], kb1);
        kb2 = fmaf(g2_wr[j], g1_bl[j], kb2);
      }
      coef[84] = kb1; coef[85] = kb2;
    }
  }

  __shared__ int part[1024];
  int chunk = (N + 1023) / 1024;
  int s0 = t * chunk, s1 = min(N, s0 + chunk);
  int sum = 0;
  for (int i = s0; i < s1; ++i) sum += cnt[i];
  part[t] = sum;
  __syncthreads();
  for (int off = 1; off < 1024; off <<= 1) {
    int v = (t >= off) ? part[t - off] : 0;
    __syncthreads();
    part[t] += v;
    __syncthreads();
  }
  int run = (t == 0) ? 0 : part[t - 1];
  for (int i = s0; i < s1; ++i) {
    row_ptr[i] = run; cursor[i] = run;
    run += cnt[i];
  }
  if (s1 == N) row_ptr[N] = run;
}

__global__ void k_scatter(const int* __restrict__ src, const int* __restrict__ dst, int E,
                          int* __restrict__ cursor, int* __restrict__ adj) {
  int e = blockIdx.x * blockDim.x + threadIdx.x;
  if (e < E) {
    int pos = atomicAdd(&cursor[dst[e]], 1);
    adj[pos] = src[e];
  }
}

// block = 64 rows x 4 threads/row; grid = rows/64 (exact).
__global__ __launch_bounds__(256, 6) void k_mlp(
    const float* __restrict__ x,
    const float* __restrict__ w_t, const float* __restrict__ b_t,
    const float* __restrict__ w_r, const float* __restrict__ b_r,
    const float* __restrict__ w_tp, const float* __restrict__ b_tp,
    const float* __restrict__ w_ssr, const float* __restrict__ b_ssr,
    const float* __restrict__ f1w, const float* __restrict__ f1b,
    const float* __restrict__ coef,
    float2* __restrict__ F1v, float2* __restrict__ F2v, int N) {
  __shared__ float S[LDS_TOT + 64 * 33];
  const int t = threadIdx.x;
  const int q = t & 3, r = t >> 2;
  const int rr = blockIdx.x * 64 + r;

  // this thread's x loads: conv-branch window (6 float4) + passthrough chunk
  const float4* xv = reinterpret_cast<const float4*>(x + (size_t)rr * 108);
  float4 bv[6];
#pragma unroll
  for (int i = 0; i < 6; ++i) bv[i] = xv[3 + 6 * q + i];
  float4 pv = make_float4(0.f, 0.f, 0.f, 0.f);
  if (q > 0) pv = xv[q - 1];

  // stage weights + coefs into LDS (overlaps x loads)
  if (t < 120) {
    S[t] = w_t[t]; S[120 + t] = w_r[t];
    S[240 + t] = w_tp[t]; S[360 + t] = w_ssr[t];
  }
  if (t < 5) {
    S[480 + t] = b_t[t]; S[485 + t] = b_r[t];
    S[490 + t] = b_tp[t]; S[495 + t] = b_ssr[t];
  }
  for (int i = t; i < 640; i += 256) {
    int o = i >> 5, k = i & 31;
    S[500 + o * 33 + k] = f1w[i];
  }
  if (t < 20) S[1160 + t] = f1b[t];
  if (t >= 128 && t < 128 + 86) S[1180 + t - 128] = coef[t - 128];
  __syncthreads();

  // conv branch q
  float acc[5];
#pragma unroll
  for (int o = 0; o < 5; ++o) acc[o] = S[480 + q * 5 + o];
#pragma unroll
  for (int i = 0; i < 6; ++i) {
    float4 w4 = bv[i];
#pragma unroll
    for (int o = 0; o < 5; ++o) {
      float4 cw = *reinterpret_cast<const float4*>(&S[q * 120 + o * 24 + 4 * i]);
      acc[o] = fmaf(w4.x, cw.x, acc[o]);
      acc[o] = fmaf(w4.y, cw.y, acc[o]);
      acc[o] = fmaf(w4.z, cw.z, acc[o]);
      acc[o] = fmaf(w4.w, cw.w, acc[o]);
    }
  }
  float* fr = &S[WFEAT + r * 33];
  if (q > 0) {
    fr[4 * (q - 1) + 0] = pv.x; fr[4 * (q - 1) + 1] = pv.y;
    fr[4 * (q - 1) + 2] = pv.z; fr[4 * (q - 1) + 3] = pv.w;
  }
#pragma unroll
  for (int o = 0; o < 5; ++o) fr[12 + q * 5 + o] = fmaxf(acc[o], 0.f);
  __syncthreads();

  // fc1 outputs o = q*5+j
  float h[5];
#pragma unroll
  for (int j = 0; j < 5; ++j) h[j] = S[1160 + q * 5 + j];
#pragma unroll
  for (int i = 0; i < 32; ++i) {
    float f = fr[i];
#pragma unroll
    for (int j = 0; j < 5; ++j)
      h[j] = fmaf(f, S[500 + (q * 5 + j) * 33 + i], h[j]);
  }
#pragma unroll
  for (int j = 0; j < 5; ++j) h[j] = fmaxf(h[j], 0.f);

  // coef partials over this thread's 5 h-values; reduce across the quad
  float pf[4];
#pragma unroll
  for (int f = 0; f < 4; ++f) {
    float s = 0.f;
#pragma unroll
    for (int j = 0; j < 5; ++j)
      s = fmaf(h[j], S[1180 + f * 20 + q * 5 + j], s);
    pf[f] = s;
  }
#pragma unroll
  for (int f = 0; f < 4; ++f) {
    pf[f] += __shfl_xor(pf[f], 1, 4);
    pf[f] += __shfl_xor(pf[f], 2, 4);
  }

  if (q == 0) {
    int b = rr / N;
    int n = rr - b * N;
    F1v[n * 16 + b] = make_float2(pf[0] + S[1180 + 80], pf[1] + S[1180 + 81]);
    F2v[n * 16 + b] = make_float2(pf[2] + S[1180 + 82], pf[3] + S[1180 + 83]);
  }
}

// 16 lanes per node (one per batch). adj read directly per lane (uniform
// within the 16-lane group -> 4 lines/instr, no shfl dependency); full chunks
// unrolled -> 16 independent gather chains in flight.
__global__ void k_agg1(const int* __restrict__ row_ptr, const int* __restrict__ adj,
                       const float2* __restrict__ F1v, const float2* __restrict__ F2v,
                       float* __restrict__ W, float* __restrict__ V, int N) {
  int t = blockIdx.x * blockDim.x + threadIdx.x;
  int g = t >> 4, b = t & 15;
  if (g >= N) return;
  int beg = row_ptr[g], end = row_ptr[g + 1];
  float sa = 0.f, sb = 0.f, sa2 = 0.f, sb2 = 0.f;
  int c = beg;
  for (; c + 16 <= end; c += 16) {
#pragma unroll
    for (int k = 0; k < 16; k += 2) {
      int s0 = adj[c + k], s1 = adj[c + k + 1];
      float2 f0 = F1v[s0 * 16 + b];
      float2 f1 = F1v[s1 * 16 + b];
      sa += f0.x; sb += f0.y;
      sa2 += f1.x; sb2 += f1.y;
    }
  }
  for (; c < end; ++c) {
    int s = adj[c];
    float2 f = F1v[s * 16 + b];
    sa += f.x; sb += f.y;
  }
  sa += sa2; sb += sb2;
  float inv = 1.0f / fmaxf((float)(end - beg), 1.0f);
  float2 f2v = F2v[t];
  W[t] = sa * inv + f2v.x;
  V[t] = sb * inv;
}

// second gather over W, fused with the final epilogue; LDS transpose so the
// out[b*N+n] write is coalesced per plane.
__global__ __launch_bounds__(256) void k_agg2(
    const int* __restrict__ row_ptr, const int* __restrict__ adj,
    const float* __restrict__ W, const float* __restrict__ V,
    const float2* __restrict__ F2v, const float* __restrict__ coef,
    const float* __restrict__ g2_bl, float* __restrict__ out, int N) {
  __shared__ float tile[16][17];
  int t = blockIdx.x * 256 + threadIdx.x;
  int g = t >> 4, b = t & 15;
  float r = 0.f;
  if (g < N) {
    int beg = row_ptr[g], end = row_ptr[g + 1];
    float sw = 0.f, sw2 = 0.f;
    int c = beg;
    for (; c + 16 <= end; c += 16) {
#pragma unroll
      for (int k = 0; k < 16; k += 2) {
        int s0 = adj[c + k], s1 = adj[c + k + 1];
        sw += W[s0 * 16 + b];
        sw2 += W[s1 * 16 + b];
      }
    }
    for (; c < end; ++c) {
      int s = adj[c];
      sw += W[s * 16 + b];
    }
    sw += sw2;
    int deg = end - beg;
    float inv = 1.0f / fmaxf((float)deg, 1.0f);
    float chi = deg > 0 ? 1.f : 0.f;
    r = sw * inv + V[t] + F2v[t].y + coef[84] * chi + coef[85] + g2_bl[0];
  }
  int gl = (threadIdx.x >> 4);
  tile[b][gl] = r;
  __syncthreads();
  int b2 = threadIdx.x >> 4;
  int gl2 = threadIdx.x & 15;
  int n2 = blockIdx.x * 16 + gl2;
  if (n2 < N) out[(size_t)b2 * N + n2] = tile[b2][gl2];
}

extern "C" void kernel_launch(void* const* d_in, const int* in_sizes, int n_in,
                              void* d_out, int out_size, void* d_ws, size_t ws_size,
                              hipStream_t stream) {
  const float* x     = (const float*)d_in[0];
  const int*   ei    = (const int*)d_in[1];
  const float* w_t   = (const float*)d_in[2];
  const float* b_t   = (const float*)d_in[3];
  const float* w_r   = (const float*)d_in[4];
  const float* b_r   = (const float*)d_in[5];
  const float* w_tp  = (const float*)d_in[6];
  const float* b_tp  = (const float*)d_in[7];
  const float* w_ssr = (const float*)d_in[8];
  const float* b_ssr = (const float*)d_in[9];
  const float* f1w   = (const float*)d_in[10];
  const float* f1b   = (const float*)d_in[11];
  const float* f2w   = (const float*)d_in[12];
  const float* f2b   = (const float*)d_in[13];
  const float* g1_wl = (const float*)d_in[14];
  const float* g1_bl = (const float*)d_in[15];
  const float* g1_wr = (const float*)d_in[16];
  const float* g2_wl = (const float*)d_in[17];
  const float* g2_bl = (const float*)d_in[18];
  const float* g2_wr = (const float*)d_in[19];
  float* out = (float*)d_out;

  const int E = in_sizes[1] / 2;
  const int N = out_size / 16;   // B = 16
  const int rows = out_size;     // N * B = 320000
  const int* src = ei;
  const int* dst = ei + E;

  // workspace
  float* ws  = (float*)d_ws;
  float2* F1v = (float2*)ws;                    // 16N float2
  float2* F2v = F1v + (size_t)16 * N;           // 16N float2
  float*  W   = (float*)(F2v + (size_t)16 * N); // 16N f32
  float*  V   = W + (size_t)16 * N;             // 16N f32
  float*  coef = V + (size_t)16 * N;            // 86
  int* cnt     = (int*)(coef + 128);            // N
  int* row_ptr = cnt + N;                       // N+1
  int* cursor  = row_ptr + N + 1;               // N
  int* adj     = cursor + N;                    // E

  int nb16 = (N * 16 + 255) / 256;

  hipMemsetAsync(cnt, 0, (size_t)N * sizeof(int), stream);
  k_count<<<(E + 255) / 256, 256, 0, stream>>>(dst, E, cnt);
  k_scan<<<1, 1024, 0, stream>>>(cnt, N, row_ptr, cursor,
                                 f2w, f2b, g1_wl, g1_bl, g1_wr, g2_wl, g2_wr, coef);
  k_scatter<<<(E + 255) / 256, 256, 0, stream>>>(src, dst, E, cursor, adj);
  k_mlp<<<rows / 64, 256, 0, stream>>>(
      x, w_t, b_t, w_r, b_r, w_tp, b_tp, w_ssr, b_ssr,
      f1w, f1b, coef, F1v, F2v, N);
  k_agg1<<<nb16, 256, 0, stream>>>(row_ptr, adj, F1v, F2v, W, V, N);
  k_agg2<<<nb16, 256, 0, stream>>>(row_ptr, adj, W, V, F2v, coef, g2_bl, out, N);
}

// Round 12
// 144.885 us; speedup vs baseline: 1.9704x; 1.9704x over previous
//
#include <hip/hip_runtime.h>

// ---------------------------------------------------------------------------
// CNN + FC + 2x GraphSAGE, collapsed to scalar fields (GNN part is linear).
// fc2 + both SAGE layers folded into coefficients (k_scan, padded layout).
// k_mlp: 4 threads/row, x staged coalesced into LDS (PAD 132); ALL LDS weight
// reads vectorized to b128 (f1w stride 36, coef [f][q][8]); feat exchange is
// intra-wave (quad = same wave) -> lgkmcnt+sched_barrier, no syncthreads.
// Aggregation via per-call CSR + register gather, direct per-lane adj reads.
// ---------------------------------------------------------------------------

#define PADX 132
#define CW   8448        // conv weights 4 x 120
#define CBv  8928        // conv bias 20
#define F1W  8948        // fc1 weights 20 rows x stride 36
#define F1B  9668        // fc1 bias 20
#define CB   9688        // coef: [f][q][8] = 128, extras 128..133 (pad 136)
#define FEAT 9824        // conv-out 64 rows x stride 28
#define LTOT 11616       // floats = 46.4 KB -> 3 blocks/CU

__global__ void k_count(const int* __restrict__ dst, int E, int* __restrict__ cnt) {
  int e = blockIdx.x * blockDim.x + threadIdx.x;
  if (e < E) atomicAdd(&cnt[dst[e]], 1);
}

// single block: weight folding (threads 0..20) + exclusive scan of cnt
__global__ __launch_bounds__(1024) void k_scan(
    const int* __restrict__ cnt, int N,
    int* __restrict__ row_ptr, int* __restrict__ cursor,
    const float* __restrict__ f2w, const float* __restrict__ f2b,
    const float* __restrict__ g1_wl, const float* __restrict__ g1_bl,
    const float* __restrict__ g1_wr, const float* __restrict__ g2_wl,
    const float* __restrict__ g2_wr, float* __restrict__ coef) {
  int t = threadIdx.x;

  if (t < 21) {
    float a[5], r1[5], c[5], r2[5];
#pragma unroll
    for (int k = 0; k < 5; ++k) { a[k] = 0.f; r1[k] = 0.f; c[k] = 0.f; r2[k] = 0.f; }
#pragma unroll
    for (int j = 0; j < 20; ++j) {
      float wl2 = g2_wl[j], wr2 = g2_wr[j];
#pragma unroll
      for (int k = 0; k < 5; ++k) {
        float wl1 = g1_wl[j * 5 + k], wr1 = g1_wr[j * 5 + k];
        a[k]  = fmaf(wl2, wl1, a[k]);
        r1[k] = fmaf(wr2, wl1, r1[k]);
        c[k]  = fmaf(wl2, wr1, c[k]);
        r2[k] = fmaf(wr2, wr1, r2[k]);
      }
    }
    if (t < 20) {
      // neuron t = q*5+j -> coef[f*32 + q*8 + j]
      int q = t / 5, j = t - 5 * q;
      float A = 0.f, R1 = 0.f, C = 0.f, R2 = 0.f;
#pragma unroll
      for (int k = 0; k < 5; ++k) {
        float w = f2w[k * 20 + t];
        A  = fmaf(a[k],  w, A);
        R1 = fmaf(r1[k], w, R1);
        C  = fmaf(c[k],  w, C);
        R2 = fmaf(r2[k], w, R2);
      }
      coef[0 * 32 + q * 8 + j] = A;
      coef[1 * 32 + q * 8 + j] = R1;
      coef[2 * 32 + q * 8 + j] = C;
      coef[3 * 32 + q * 8 + j] = R2;
    } else {
      float ca = 0.f, cr1 = 0.f, cc = 0.f, cr2 = 0.f;
#pragma unroll
      for (int k = 0; k < 5; ++k) {
        float b = f2b[k];
        ca = fmaf(a[k], b, ca);  cr1 = fmaf(r1[k], b, cr1);
        cc = fmaf(c[k], b, cc);  cr2 = fmaf(r2[k], b, cr2);
      }
      coef[128] = ca; coef[129] = cr1; coef[130] = cc; coef[131] = cr2;
      float kb1 = 0.f, kb2 = 0.f;
#pragma unroll
      for (int j = 0; j < 20; ++j) {
        kb1 = fmaf(g2_wl[j], g1_bl[j], kb1);
        kb2 = fmaf(g2_wr[j], g1_bl[j], kb2);
      }
      coef[132] = kb1; coef[133] = kb2;
    }
  }

  __shared__ int part[1024];
  int chunk = (N + 1023) / 1024;
  int s0 = t * chunk, s1 = min(N, s0 + chunk);
  int sum = 0;
  for (int i = s0; i < s1; ++i) sum += cnt[i];
  part[t] = sum;
  __syncthreads();
  for (int off = 1; off < 1024; off <<= 1) {
    int v = (t >= off) ? part[t - off] : 0;
    __syncthreads();
    part[t] += v;
    __syncthreads();
  }
  int run = (t == 0) ? 0 : part[t - 1];
  for (int i = s0; i < s1; ++i) {
    row_ptr[i] = run; cursor[i] = run;
    run += cnt[i];
  }
  if (s1 == N) row_ptr[N] = run;
}

__global__ void k_scatter(const int* __restrict__ src, const int* __restrict__ dst, int E,
                          int* __restrict__ cursor, int* __restrict__ adj) {
  int e = blockIdx.x * blockDim.x + threadIdx.x;
  if (e < E) {
    int pos = atomicAdd(&cursor[dst[e]], 1);
    adj[pos] = src[e];
  }
}

// block = 64 rows x 4 threads/row; grid = rows/64 (exact).
__global__ __launch_bounds__(256) void k_mlp(
    const float* __restrict__ x,
    const float* __restrict__ w_t, const float* __restrict__ b_t,
    const float* __restrict__ w_r, const float* __restrict__ b_r,
    const float* __restrict__ w_tp, const float* __restrict__ b_tp,
    const float* __restrict__ w_ssr, const float* __restrict__ b_ssr,
    const float* __restrict__ f1w, const float* __restrict__ f1b,
    const float* __restrict__ coef,
    float2* __restrict__ F1v, float2* __restrict__ F2v, int N) {
  __shared__ float S[LTOT];
  const int t = threadIdx.x;
  const int q = t & 3, r = t >> 2;

  // ---- coalesced x load: 7 x 1KB-contiguous-per-wave ----
  float4 ld[7];
  const float4* xs = reinterpret_cast<const float4*>(x + (size_t)blockIdx.x * 64 * 108);
#pragma unroll
  for (int i = 0; i < 7; ++i) {
    int c = i * 256 + t;
    ld[i] = xs[c < 1728 ? c : 1727];
  }

  // ---- stage weights + coefs (independent, overlaps x loads) ----
  if (t < 120) {
    S[CW + t] = w_t[t]; S[CW + 120 + t] = w_r[t];
    S[CW + 240 + t] = w_tp[t]; S[CW + 360 + t] = w_ssr[t];
  }
  if (t < 5) {
    S[CBv + t] = b_t[t]; S[CBv + 5 + t] = b_r[t];
    S[CBv + 10 + t] = b_tp[t]; S[CBv + 15 + t] = b_ssr[t];
  }
  for (int i = t; i < 640; i += 256) {
    int o = i >> 5, k = i & 31;
    S[F1W + o * 36 + k] = f1w[i];
  }
  if (t < 20) S[F1B + t] = f1b[t];
  if (t >= 120 && t < 120 + 136) S[CB + t - 120] = coef[t - 120];

  // ---- scatter x chunks into PAD-132 rows ----
#pragma unroll
  for (int i = 0; i < 7; ++i) {
    int c = i * 256 + t;
    if (c < 1728) {
      int row = c / 27, part = c - row * 27;
      *reinterpret_cast<float4*>(&S[row * PADX + part * 4]) = ld[i];
    }
  }
  __syncthreads();

  // ---- conv branch q of row r (all b128 LDS reads) ----
  const float* xr = &S[r * PADX];
  float acc[5];
#pragma unroll
  for (int o = 0; o < 5; ++o) acc[o] = S[CBv + q * 5 + o];
#pragma unroll
  for (int i = 0; i < 6; ++i) {
    float4 w4 = *reinterpret_cast<const float4*>(xr + 12 + 24 * q + 4 * i);
#pragma unroll
    for (int o = 0; o < 5; ++o) {
      float4 cw = *reinterpret_cast<const float4*>(&S[CW + q * 120 + o * 24 + 4 * i]);
      acc[o] = fmaf(w4.x, cw.x, acc[o]);
      acc[o] = fmaf(w4.y, cw.y, acc[o]);
      acc[o] = fmaf(w4.z, cw.z, acc[o]);
      acc[o] = fmaf(w4.w, cw.w, acc[o]);
    }
  }
  float* fr = &S[FEAT + r * 28];
#pragma unroll
  for (int o = 0; o < 5; ++o) fr[q * 5 + o] = fmaxf(acc[o], 0.f);
  // quad (4 threads of row r) is intra-wave: drain LDS, forbid reordering
  asm volatile("s_waitcnt lgkmcnt(0)" ::: "memory");
  __builtin_amdgcn_sched_barrier(0);

  // ---- fc1 outputs o = q*5+j; inputs 0..11 from xr, 12..31 from fr ----
  float h[5];
#pragma unroll
  for (int j = 0; j < 5; ++j) h[j] = S[F1B + q * 5 + j];
#pragma unroll
  for (int i4 = 0; i4 < 3; ++i4) {
    float4 fv = *reinterpret_cast<const float4*>(xr + 4 * i4);
#pragma unroll
    for (int j = 0; j < 5; ++j) {
      float4 wv = *reinterpret_cast<const float4*>(&S[F1W + (q * 5 + j) * 36 + 4 * i4]);
      h[j] = fmaf(fv.x, wv.x, h[j]);
      h[j] = fmaf(fv.y, wv.y, h[j]);
      h[j] = fmaf(fv.z, wv.z, h[j]);
      h[j] = fmaf(fv.w, wv.w, h[j]);
    }
  }
#pragma unroll
  for (int i4 = 0; i4 < 5; ++i4) {
    float4 fv = *reinterpret_cast<const float4*>(fr + 4 * i4);
#pragma unroll
    for (int j = 0; j < 5; ++j) {
      float4 wv = *reinterpret_cast<const float4*>(&S[F1W + (q * 5 + j) * 36 + 12 + 4 * i4]);
      h[j] = fmaf(fv.x, wv.x, h[j]);
      h[j] = fmaf(fv.y, wv.y, h[j]);
      h[j] = fmaf(fv.z, wv.z, h[j]);
      h[j] = fmaf(fv.w, wv.w, h[j]);
    }
  }
#pragma unroll
  for (int j = 0; j < 5; ++j) h[j] = fmaxf(h[j], 0.f);

  // ---- folded coef partials (b128 reads), reduce across the quad ----
  float pf[4];
#pragma unroll
  for (int f = 0; f < 4; ++f) {
    float4 c0 = *reinterpret_cast<const float4*>(&S[CB + f * 32 + q * 8]);
    float c4 = S[CB + f * 32 + q * 8 + 4];
    float s = h[0] * c0.x;
    s = fmaf(h[1], c0.y, s);
    s = fmaf(h[2], c0.z, s);
    s = fmaf(h[3], c0.w, s);
    s = fmaf(h[4], c4, s);
    pf[f] = s;
  }
#pragma unroll
  for (int f = 0; f < 4; ++f) {
    pf[f] += __shfl_xor(pf[f], 1, 4);
    pf[f] += __shfl_xor(pf[f], 2, 4);
  }

  if (q == 0) {
    int rr = blockIdx.x * 64 + r;
    int b = rr / N;
    int n = rr - b * N;
    F1v[n * 16 + b] = make_float2(pf[0] + S[CB + 128], pf[1] + S[CB + 129]);
    F2v[n * 16 + b] = make_float2(pf[2] + S[CB + 130], pf[3] + S[CB + 131]);
  }
}

// 16 lanes per node (one per batch); adj read directly per lane, unrolled.
__global__ void k_agg1(const int* __restrict__ row_ptr, const int* __restrict__ adj,
                       const float2* __restrict__ F1v, const float2* __restrict__ F2v,
                       float* __restrict__ W, float* __restrict__ V, int N) {
  int t = blockIdx.x * blockDim.x + threadIdx.x;
  int g = t >> 4, b = t & 15;
  if (g >= N) return;
  int beg = row_ptr[g], end = row_ptr[g + 1];
  float sa = 0.f, sb = 0.f, sa2 = 0.f, sb2 = 0.f;
  int c = beg;
  for (; c + 16 <= end; c += 16) {
#pragma unroll
    for (int k = 0; k < 16; k += 2) {
      int s0 = adj[c + k], s1 = adj[c + k + 1];
      float2 f0 = F1v[s0 * 16 + b];
      float2 f1 = F1v[s1 * 16 + b];
      sa += f0.x; sb += f0.y;
      sa2 += f1.x; sb2 += f1.y;
    }
  }
  for (; c < end; ++c) {
    int s = adj[c];
    float2 f = F1v[s * 16 + b];
    sa += f.x; sb += f.y;
  }
  sa += sa2; sb += sb2;
  float inv = 1.0f / fmaxf((float)(end - beg), 1.0f);
  float2 f2v = F2v[t];
  W[t] = sa * inv + f2v.x;
  V[t] = sb * inv;
}

// second gather over W, fused with the final epilogue; LDS transpose so the
// out[b*N+n] write is coalesced per plane.
__global__ __launch_bounds__(256) void k_agg2(
    const int* __restrict__ row_ptr, const int* __restrict__ adj,
    const float* __restrict__ W, const float* __restrict__ V,
    const float2* __restrict__ F2v, const float* __restrict__ coef,
    const float* __restrict__ g2_bl, float* __restrict__ out, int N) {
  __shared__ float tile[16][17];
  int t = blockIdx.x * 256 + threadIdx.x;
  int g = t >> 4, b = t & 15;
  float r = 0.f;
  if (g < N) {
    int beg = row_ptr[g], end = row_ptr[g + 1];
    float sw = 0.f, sw2 = 0.f;
    int c = beg;
    for (; c + 16 <= end; c += 16) {
#pragma unroll
      for (int k = 0; k < 16; k += 2) {
        int s0 = adj[c + k], s1 = adj[c + k + 1];
        sw += W[s0 * 16 + b];
        sw2 += W[s1 * 16 + b];
      }
    }
    for (; c < end; ++c) {
      int s = adj[c];
      sw += W[s * 16 + b];
    }
    sw += sw2;
    int deg = end - beg;
    float inv = 1.0f / fmaxf((float)deg, 1.0f);
    float chi = deg > 0 ? 1.f : 0.f;
    r = sw * inv + V[t] + F2v[t].y + coef[132] * chi + coef[133] + g2_bl[0];
  }
  int gl = (threadIdx.x >> 4);
  tile[b][gl] = r;
  __syncthreads();
  int b2 = threadIdx.x >> 4;
  int gl2 = threadIdx.x & 15;
  int n2 = blockIdx.x * 16 + gl2;
  if (n2 < N) out[(size_t)b2 * N + n2] = tile[b2][gl2];
}

extern "C" void kernel_launch(void* const* d_in, const int* in_sizes, int n_in,
                              void* d_out, int out_size, void* d_ws, size_t ws_size,
                              hipStream_t stream) {
  const float* x     = (const float*)d_in[0];
  const int*   ei    = (const int*)d_in[1];
  const float* w_t   = (const float*)d_in[2];
  const float* b_t   = (const float*)d_in[3];
  const float* w_r   = (const float*)d_in[4];
  const float* b_r   = (const float*)d_in[5];
  const float* w_tp  = (const float*)d_in[6];
  const float* b_tp  = (const float*)d_in[7];
  const float* w_ssr = (const float*)d_in[8];
  const float* b_ssr = (const float*)d_in[9];
  const float* f1w   = (const float*)d_in[10];
  const float* f1b   = (const float*)d_in[11];
  const float* f2w   = (const float*)d_in[12];
  const float* f2b   = (const float*)d_in[13];
  const float* g1_wl = (const float*)d_in[14];
  const float* g1_bl = (const float*)d_in[15];
  const float* g1_wr = (const float*)d_in[16];
  const float* g2_wl = (const float*)d_in[17];
  const float* g2_bl = (const float*)d_in[18];
  const float* g2_wr = (const float*)d_in[19];
  float* out = (float*)d_out;

  const int E = in_sizes[1] / 2;
  const int N = out_size / 16;   // B = 16
  const int rows = out_size;     // N * B = 320000
  const int* src = ei;
  const int* dst = ei + E;

  // workspace
  float* ws  = (float*)d_ws;
  float2* F1v = (float2*)ws;                    // 16N float2
  float2* F2v = F1v + (size_t)16 * N;           // 16N float2
  float*  W   = (float*)(F2v + (size_t)16 * N); // 16N f32
  float*  V   = W + (size_t)16 * N;             // 16N f32
  float*  coef = V + (size_t)16 * N;            // 136 (padded 160)
  int* cnt     = (int*)(coef + 160);            // N
  int* row_ptr = cnt + N;                       // N+1
  int* cursor  = row_ptr + N + 1;               // N
  int* adj     = cursor + N;                    // E

  int nb16 = (N * 16 + 255) / 256;

  hipMemsetAsync(cnt, 0, (size_t)N * sizeof(int), stream);
  k_count<<<(E + 255) / 256, 256, 0, stream>>>(dst, E, cnt);
  k_scan<<<1, 1024, 0, stream>>>(cnt, N, row_ptr, cursor,
                                 f2w, f2b, g1_wl, g1_bl, g1_wr, g2_wl, g2_wr, coef);
  k_scatter<<<(E + 255) / 256, 256, 0, stream>>>(src, dst, E, cursor, adj);
  k_mlp<<<rows / 64, 256, 0, stream>>>(
      x, w_t, b_t, w_r, b_r, w_tp, b_tp, w_ssr, b_ssr,
      f1w, f1b, coef, F1v, F2v, N);
  k_agg1<<<nb16, 256, 0, stream>>>(row_ptr, adj, F1v, F2v, W, V, N);
  k_agg2<<<nb16, 256, 0, stream>>>(row_ptr, adj, W, V, F2v, coef, g2_bl, out, N);
}